// Round 7
// baseline (75.557 us; speedup 1.0000x reference)
//
#include <hip/hip_runtime.h>
#include <math.h>

#define BATCH 32
#define CH    256
#define HH    64
#define WW    64
#define HW    (HH * WW)                  // 4096
#define NPIX  (BATCH * HW)               // 131072
#define NTOT  ((size_t)BATCH * CH * HW)  // 33554432

typedef float floatx4 __attribute__((ext_vector_type(4)));

// K1: channel-wise mean+max -> pooled. Block = 64 pixels x 256 channels.
// 2048 blocks x 256 threads -> 8 blocks/CU = 32 waves/CU (max occupancy).
// Thread (g = t&15 pixel-group, c = t>>4 chunk of 16 channels).
#define K1_GRP 16
#define K1_CHUNKS 16
#define K1_CCH 16
__global__ __launch_bounds__(256) void sa_pool(
    const float* __restrict__ x, float4* __restrict__ pooled4) {
    __shared__ float4 sS[K1_CHUNKS][K1_GRP];
    __shared__ float4 sM[K1_CHUNKS][K1_GRP];
    int t = threadIdx.x;
    int g = t & 15;
    int c = t >> 4;
    int img = blockIdx.x >> 6;           // 64 blocks per image
    int seg = blockIdx.x & 63;           // 64-pixel strip
    int pix0 = seg * 64;
    const float* p = x + (size_t)img * CH * HW + (size_t)c * K1_CCH * HW
                   + pix0 + g * 4;
    float4 s = make_float4(0.f, 0.f, 0.f, 0.f);
    float4 m = make_float4(-INFINITY, -INFINITY, -INFINITY, -INFINITY);
#pragma unroll 8
    for (int i = 0; i < K1_CCH; ++i) {
        float4 v = *reinterpret_cast<const float4*>(p + (size_t)i * HW);
        s.x += v.x; s.y += v.y; s.z += v.z; s.w += v.w;
        m.x = fmaxf(m.x, v.x); m.y = fmaxf(m.y, v.y);
        m.z = fmaxf(m.z, v.z); m.w = fmaxf(m.w, v.w);
    }
    sS[c][g] = s;
    sM[c][g] = m;
    __syncthreads();
    if (t < K1_GRP) {
        float4 as = sS[0][t];
        float4 am = sM[0][t];
#pragma unroll
        for (int cc = 1; cc < K1_CHUNKS; ++cc) {
            float4 bs = sS[cc][t];
            float4 bm = sM[cc][t];
            as.x += bs.x; as.y += bs.y; as.z += bs.z; as.w += bs.w;
            am.x = fmaxf(am.x, bm.x); am.y = fmaxf(am.y, bm.y);
            am.z = fmaxf(am.z, bm.z); am.w = fmaxf(am.w, bm.w);
        }
        const float inv = 1.0f / (float)CH;
        float4 o;
        o.x = as.x * inv + am.x; o.y = as.y * inv + am.y;
        o.z = as.z * inv + am.z; o.w = as.w * inv + am.w;
        pooled4[(img * HW + pix0) / 4 + t] = o;
    }
}

// K2: 7x7 SAME conv + bias + sigmoid -> attn. 512 blocks x 256.
__global__ __launch_bounds__(256) void sa_conv(
    const float* __restrict__ pooled, const float* __restrict__ wgt,
    const float* __restrict__ bias, float* __restrict__ attn) {
    int idx = blockIdx.x * blockDim.x + threadIdx.x;
    if (idx >= NPIX) return;
    int b  = idx >> 12;
    int hw = idx & 4095;
    int h  = hw >> 6;
    int w  = hw & 63;
    const float* pb = pooled + b * HW;
    float acc = bias[0];
#pragma unroll
    for (int kh = 0; kh < 7; ++kh) {
        int hh2 = h + kh - 3;
        if (hh2 < 0 || hh2 >= HH) continue;
#pragma unroll
        for (int kw = 0; kw < 7; ++kw) {
            int ww2 = w + kw - 3;
            if (ww2 < 0 || ww2 >= WW) continue;
            acc += pb[hh2 * WW + ww2] * wgt[kh * 7 + kw];
        }
    }
    attn[idx] = 1.0f / (1.0f + __expf(-acc));
}

// K3: out = x * attn. 8 consecutive floats (2x float4) per thread, NT stores.
// 16384 blocks x 256 threads, fully linear streaming.
__global__ __launch_bounds__(256) void sa_mul(
    const float* __restrict__ x, const float* __restrict__ attn,
    float* __restrict__ out) {
    size_t i = ((size_t)blockIdx.x * blockDim.x + threadIdx.x) * 8;
    if (i >= NTOT) return;
    // both float4s lie in the same (b,c) plane: i % 4096 <= 4088
    size_t bc = i >> 12;
    int hw    = (int)(i & 4095);
    int b     = (int)(bc >> 8);
    const float* ap = attn + (size_t)b * HW + hw;
    float4 x0 = *reinterpret_cast<const float4*>(x + i);
    float4 x1 = *reinterpret_cast<const float4*>(x + i + 4);
    float4 a0 = *reinterpret_cast<const float4*>(ap);
    float4 a1 = *reinterpret_cast<const float4*>(ap + 4);
    floatx4 o0, o1;
    o0.x = x0.x * a0.x; o0.y = x0.y * a0.y;
    o0.z = x0.z * a0.z; o0.w = x0.w * a0.w;
    o1.x = x1.x * a1.x; o1.y = x1.y * a1.y;
    o1.z = x1.z * a1.z; o1.w = x1.w * a1.w;
    __builtin_nontemporal_store(o0, reinterpret_cast<floatx4*>(out + i));
    __builtin_nontemporal_store(o1, reinterpret_cast<floatx4*>(out + i + 4));
}

extern "C" void kernel_launch(void* const* d_in, const int* in_sizes, int n_in,
                              void* d_out, int out_size, void* d_ws, size_t ws_size,
                              hipStream_t stream) {
    const float* x    = (const float*)d_in[0];
    const float* wgt  = (const float*)d_in[1];
    const float* bias = (const float*)d_in[2];
    float* out = (float*)d_out;

    // ws layout (floats): pooled [NPIX], attn [NPIX]
    float* pooled = (float*)d_ws;
    float* attn   = pooled + NPIX;

    sa_pool<<<dim3(NPIX / 64), dim3(256), 0, stream>>>(
        x, reinterpret_cast<float4*>(pooled));          // 2048 blocks
    sa_conv<<<dim3((NPIX + 255) / 256), dim3(256), 0, stream>>>(
        pooled, wgt, bias, attn);                       // 512 blocks
    sa_mul<<<dim3((unsigned)(NTOT / 8 / 256)), dim3(256), 0, stream>>>(
        x, attn, out);                                  // 16384 blocks
}

// Round 8
// 74.392 us; speedup vs baseline: 1.0157x; 1.0157x over previous
//
#include <hip/hip_runtime.h>
#include <math.h>

#define BATCH 32
#define CH    256
#define HH    64
#define WW    64
#define HW    (HH * WW)                  // 4096
#define NPIX  (BATCH * HW)               // 131072
#define NTOT  ((size_t)BATCH * CH * HW)  // 33554432

typedef float floatx4 __attribute__((ext_vector_type(4)));

// K1: channel-wise mean+max -> pooled, in-block LDS combine, float4 loads.
// Block = 128 contiguous pixels x 256 channels; 1024 blocks x 256 threads.
#define PIX_PER_BLK 128
#define GRP_PER_BLK 32
#define NCHUNK 8
#define CCHUNK 32
#define NBLK  (NPIX / PIX_PER_BLK)       // 1024
__global__ __launch_bounds__(256) void sa_pool(
    const float* __restrict__ x, float4* __restrict__ pooled4) {
    __shared__ float4 sS[NCHUNK][GRP_PER_BLK];
    __shared__ float4 sM[NCHUNK][GRP_PER_BLK];
    int t = threadIdx.x;
    int g = t & 31;
    int c = t >> 5;
    int img = blockIdx.x >> 5;           // 32 blocks per image
    int seg = blockIdx.x & 31;
    int pix0 = seg * PIX_PER_BLK;
    const float* p = x + (size_t)img * CH * HW + (size_t)c * CCHUNK * HW
                   + pix0 + g * 4;
    float4 s = make_float4(0.f, 0.f, 0.f, 0.f);
    float4 m = make_float4(-INFINITY, -INFINITY, -INFINITY, -INFINITY);
#pragma unroll 8
    for (int i = 0; i < CCHUNK; ++i) {
        float4 v = *reinterpret_cast<const float4*>(p + (size_t)i * HW);
        s.x += v.x; s.y += v.y; s.z += v.z; s.w += v.w;
        m.x = fmaxf(m.x, v.x); m.y = fmaxf(m.y, v.y);
        m.z = fmaxf(m.z, v.z); m.w = fmaxf(m.w, v.w);
    }
    sS[c][g] = s;
    sM[c][g] = m;
    __syncthreads();
    if (t < GRP_PER_BLK) {
        float4 as = sS[0][t];
        float4 am = sM[0][t];
#pragma unroll
        for (int cc = 1; cc < NCHUNK; ++cc) {
            float4 bs = sS[cc][t];
            float4 bm = sM[cc][t];
            as.x += bs.x; as.y += bs.y; as.z += bs.z; as.w += bs.w;
            am.x = fmaxf(am.x, bm.x); am.y = fmaxf(am.y, bm.y);
            am.z = fmaxf(am.z, bm.z); am.w = fmaxf(am.w, bm.w);
        }
        const float inv = 1.0f / (float)CH;
        float4 o;
        o.x = as.x * inv + am.x; o.y = as.y * inv + am.y;
        o.z = as.z * inv + am.z; o.w = as.w * inv + am.w;
        pooled4[(img * HW + pix0) / 4 + t] = o;
    }
}

// K2: 7x7 SAME conv + bias + sigmoid -> attn. 512 blocks x 256.
__global__ __launch_bounds__(256) void sa_conv(
    const float* __restrict__ pooled, const float* __restrict__ wgt,
    const float* __restrict__ bias, float* __restrict__ attn) {
    int idx = blockIdx.x * blockDim.x + threadIdx.x;
    if (idx >= NPIX) return;
    int b  = idx >> 12;
    int hw = idx & 4095;
    int h  = hw >> 6;
    int w  = hw & 63;
    const float* pb = pooled + b * HW;
    float acc = bias[0];
#pragma unroll
    for (int kh = 0; kh < 7; ++kh) {
        int hh2 = h + kh - 3;
        if (hh2 < 0 || hh2 >= HH) continue;
#pragma unroll
        for (int kw = 0; kw < 7; ++kw) {
            int ww2 = w + kw - 3;
            if (ww2 < 0 || ww2 >= WW) continue;
            acc += pb[hh2 * WW + ww2] * wgt[kh * 7 + kw];
        }
    }
    attn[idx] = 1.0f / (1.0f + __expf(-acc));
}

// K3: out = x * attn, 1 float4 per thread, REVERSED block order (consume
// x tail-first = MRU-first after pool) + NT stores (keep out from evicting
// x's L3 residency).
__global__ __launch_bounds__(256) void sa_mul(
    const float* __restrict__ x, const float* __restrict__ attn,
    float* __restrict__ out) {
    unsigned rb = gridDim.x - 1 - blockIdx.x;
    size_t i = ((size_t)rb * blockDim.x + threadIdx.x) * 4;
    if (i >= NTOT) return;
    size_t bc = i >> 12;         // b*CH + c
    int hw    = (int)(i & 4095);
    int b     = (int)(bc >> 8);
    float4 xv = *reinterpret_cast<const float4*>(x + i);
    float4 av = *reinterpret_cast<const float4*>(attn + (size_t)b * HW + hw);
    floatx4 o;
    o.x = xv.x * av.x;
    o.y = xv.y * av.y;
    o.z = xv.z * av.z;
    o.w = xv.w * av.w;
    __builtin_nontemporal_store(o, reinterpret_cast<floatx4*>(out + i));
}

extern "C" void kernel_launch(void* const* d_in, const int* in_sizes, int n_in,
                              void* d_out, int out_size, void* d_ws, size_t ws_size,
                              hipStream_t stream) {
    const float* x    = (const float*)d_in[0];
    const float* wgt  = (const float*)d_in[1];
    const float* bias = (const float*)d_in[2];
    float* out = (float*)d_out;

    // ws layout (floats): pooled [NPIX], attn [NPIX]
    float* pooled = (float*)d_ws;
    float* attn   = pooled + NPIX;

    sa_pool<<<dim3(NBLK), dim3(256), 0, stream>>>(
        x, reinterpret_cast<float4*>(pooled));
    sa_conv<<<dim3((NPIX + 255) / 256), dim3(256), 0, stream>>>(
        pooled, wgt, bias, attn);
    sa_mul<<<dim3((unsigned)(NTOT / 4 / 256)), dim3(256), 0, stream>>>(
        x, attn, out);
}